// Round 15
// baseline (193.381 us; speedup 1.0000x reference)
//
#include <hip/hip_runtime.h>
#include <hip/hip_bf16.h>
#include <math.h>

#define H 2048
#define W 4096
#define NPIX (H * W)
#define KSEL 4194303u   // (N-1)/2, 0-indexed order statistic for lower median
#define NT 512          // threads per block for k_final
#define TSX 64          // k_final tile width
#define TSY 32          // k_final tile height
#define NBX (W / TSX)   // 64

__device__ __forceinline__ unsigned fmap(float f) {
    unsigned u = __float_as_uint(f);
    return (u & 0x80000000u) ? ~u : (u | 0x80000000u);
}
__device__ __forceinline__ float4 ld4s(const float* p) { return *(const float4*)p; }
__device__ __forceinline__ void st4s(float* p, float4 v) { *(float4*)p = v; }
__device__ __forceinline__ void ld12(const float* p, float* d) {
    float4 a = ld4s(p), b = ld4s(p + 4), c = ld4s(p + 8);
    d[0]=a.x; d[1]=a.y; d[2]=a.z; d[3]=a.w;
    d[4]=b.x; d[5]=b.y; d[6]=b.z; d[7]=b.w;
    d[8]=c.x; d[9]=c.y; d[10]=c.z; d[11]=c.w;
}

// ---------------- Pass A: fused sobel+hgauss (R14-proven body), tile 64x16, NT=256 ----------------
// 25.2 KB LDS -> 6 blocks/CU (vs 3): barriers idle 1/6 of CU instead of 1/3.
// LDS layout (floats):
//   sx : 0    .. 1824   (24 rows x 76)  [lh 256 uints overlay @0 after fused phase]
//   h0 : 1824 .. 3320   (22 rows x 68)
//   h1 : 3320 .. 4816
//   h2 : 4816 .. 6312
#define SMF 6312
#define SXB(r,c) smem[(r)*76 + (c)]
#define H0B(r,c) smem[1824 + (r)*68 + (c)]
#define H1B(r,c) smem[3320 + (r)*68 + (c)]
#define H2B(r,c) smem[4816 + (r)*68 + (c)]

__global__ __launch_bounds__(256) void k_response(const float* __restrict__ x,
                                                  const float* __restrict__ gw,
                                                  float* __restrict__ r,
                                                  unsigned* __restrict__ hist1) {
    __shared__ float smem[SMF];
    unsigned* lh = (unsigned*)smem;   // overlays sx (dead after fused phase)

    int tl = threadIdx.x;
    int bx = blockIdx.x & 63;
    int by = blockIdx.x >> 6;        // 0..127
    int tx0 = bx * 64, ty0 = by * 16;
    bool interior = ((unsigned)(bx - 1) < 62u) && ((unsigned)(by - 1) < 126u);

    float hwr[7], vwr[7];
    float g33 = gw[24];
#pragma unroll
    for (int b = 0; b < 7; ++b) hwr[b] = gw[21 + b];
#pragma unroll
    for (int a = 0; a < 7; ++a) vwr[a] = gw[a * 7 + 3] / g33;

    // ---- phase 1: load x tile rows ty0-4..ty0+19 (24), cols tx0-4..tx0+67 (72 = 18 groups) ----
#pragma unroll
    for (int it = 0; it < 2; ++it) {
        int task = tl + it * 256;
        if (task < 432) {
            int row = task / 18, g = task - row * 18;
            int gy = ty0 - 4 + row;
            int gx0 = tx0 - 4 + 4 * g;
            float4 v;
            if (interior) {
                v = *(const float4*)&x[(size_t)gy * W + gx0];
            } else {
                v = make_float4(0.f, 0.f, 0.f, 0.f);
                if ((unsigned)gy < H) {
                    if ((unsigned)gx0 <= (unsigned)(W - 4)) {
                        v = *(const float4*)&x[(size_t)gy * W + gx0];
                    } else {
                        float* vv = (float*)&v;
#pragma unroll
                        for (int k = 0; k < 4; ++k) {
                            int c = gx0 + k;
                            if ((unsigned)c < W) vv[k] = x[(size_t)gy * W + c];
                        }
                    }
                }
            }
            st4s(&SXB(row, 4 * g), v);
        }
    }
    __syncthreads();

    // ---- phase 2 (fused): sobel on the fly + horizontal gaussian of products ----
    // task (row 0..21, c0 0..60): h[row][c0..c0+3]; gradient p at image col tx0+c0+p-3,
    // image row ty0-3+row. Register-pinned staging (R14-proven) prevents LDS re-reads.
#pragma unroll
    for (int it = 0; it < 2; ++it) {
        int task = tl + it * 256;
        if (task < 352) {
            int row = task >> 4;
            int c0 = (task & 15) << 2;
            int xbase = tx0 + c0 - 3;

            float x0[12], x1[12], x2[12];
            ld12(&SXB(row, c0), x0);
            ld12(&SXB(row + 1, c0), x1);
            ld12(&SXB(row + 2, c0), x2);
#pragma unroll
            for (int p = 0; p < 12; ++p)
                asm volatile("" : "+v"(x0[p]), "+v"(x1[p]), "+v"(x2[p]));

            float px[10], py[10], pxy[10];
            if (interior) {
#pragma unroll
                for (int p = 0; p < 10; ++p) {
                    float ix = (x0[p + 2] - x0[p]) + 2.f * (x1[p + 2] - x1[p]) + (x2[p + 2] - x2[p]);
                    float iy = (x2[p] - x0[p]) + 2.f * (x2[p + 1] - x0[p + 1]) + (x2[p + 2] - x0[p + 2]);
                    px[p] = ix * ix; py[p] = iy * iy; pxy[p] = ix * iy;
                }
            } else {
                int rowOK = ((unsigned)(ty0 - 3 + row) < H);
#pragma unroll
                for (int p = 0; p < 10; ++p) {
                    float ix = (x0[p + 2] - x0[p]) + 2.f * (x1[p + 2] - x1[p]) + (x2[p + 2] - x2[p]);
                    float iy = (x2[p] - x0[p]) + 2.f * (x2[p + 1] - x0[p + 1]) + (x2[p + 2] - x0[p + 2]);
                    bool ok = rowOK && ((unsigned)(xbase + p) < W);
                    ix = ok ? ix : 0.f;
                    iy = ok ? iy : 0.f;
                    px[p] = ix * ix; py[p] = iy * iy; pxy[p] = ix * iy;
                }
            }

            float4 s0, s1, s2;
            float* q0 = (float*)&s0; float* q1 = (float*)&s1; float* q2 = (float*)&s2;
#pragma unroll
            for (int k = 0; k < 4; ++k) {
                float a0 = 0.f, a1 = 0.f, a2 = 0.f;
#pragma unroll
                for (int b = 0; b < 7; ++b) {
                    float w = hwr[b];
                    a0 += w * px[k + b];
                    a1 += w * py[k + b];
                    a2 += w * pxy[k + b];
                }
                q0[k] = a0; q1[k] = a1; q2[k] = a2;
            }
            st4s(&H0B(row, c0), s0);
            st4s(&H1B(row, c0), s1);
            st4s(&H2B(row, c0), s2);
        }
    }
    __syncthreads();

    // ---- zero lh (overlays sx, now dead) ----
    lh[tl] = 0;
    __syncthreads();

    // ---- vertical gaussian + response + merged-bin histogram: 16 rows x 16 groups = 256 ----
    {
        int ii = tl >> 4, c0 = (tl & 15) << 2;
        float4 a0 = make_float4(0.f, 0.f, 0.f, 0.f), a1 = a0, a2 = a0;
#pragma unroll
        for (int a = 0; a < 7; ++a) {
            float w = vwr[a];
            float4 h0v = ld4s(&H0B(ii + a, c0));
            float4 h1v = ld4s(&H1B(ii + a, c0));
            float4 h2v = ld4s(&H2B(ii + a, c0));
            a0.x += w * h0v.x; a0.y += w * h0v.y; a0.z += w * h0v.z; a0.w += w * h0v.w;
            a1.x += w * h1v.x; a1.y += w * h1v.y; a1.z += w * h1v.z; a1.w += w * h1v.w;
            a2.x += w * h2v.x; a2.y += w * h2v.y; a2.z += w * h2v.z; a2.w += w * h2v.w;
        }
        float* sxx = (float*)&a0; float* syy = (float*)&a1; float* sxy = (float*)&a2;
        float4 rv4;
        float* prv = (float*)&rv4;
#pragma unroll
        for (int k = 0; k < 4; ++k) {
            float tr = sxx[k] + syy[k];
            prv[k] = sxx[k] * syy[k] - sxy[k] * sxy[k] - 0.05f * tr * tr;
        }
        st4s(&r[(size_t)(ty0 + ii) * W + tx0 + c0], rv4);
        unsigned bn[4];
#pragma unroll
        for (int k = 0; k < 4; ++k) bn[k] = fmap(prv[k]) >> 24;
#pragma unroll
        for (int i = 0; i < 4; ++i) {
            bool dup = false;
            unsigned cnt = 1;
#pragma unroll
            for (int j = 0; j < 4; ++j) {
                if (j < i) dup = dup || (bn[j] == bn[i]);
                if (j > i) cnt += (bn[j] == bn[i]) ? 1u : 0u;
            }
            if (!dup) atomicAdd(&lh[bn[i]], cnt);
        }
    }
    __syncthreads();
    if (lh[tl]) atomicAdd(&hist1[tl], lh[tl]);
}

// ---------------- 256-bin scan (R11-proven) ----------------
__global__ __launch_bounds__(256) void k_scan256(const unsigned* __restrict__ hist,
                                                 unsigned* __restrict__ sel,
                                                 int in_rank_idx, int out_base) {
    __shared__ unsigned s[256];
    int t = threadIdx.x;
    unsigned c = hist[t];
    s[t] = c;
    __syncthreads();
    for (int off = 1; off < 256; off <<= 1) {
        unsigned v = (t >= off) ? s[t - off] : 0u;
        __syncthreads();
        s[t] += v;
        __syncthreads();
    }
    unsigned k = (in_rank_idx < 0) ? KSEL : sel[in_rank_idx];
    unsigned cumb = s[t] - c;
    if (k >= cumb && k < s[t]) {
        sel[out_base] = (unsigned)t;
        sel[out_base + 1] = k - cumb;
    }
}

// ---------------- hist2 (R11-proven body; grid 2048) ----------------
__global__ __launch_bounds__(256) void k_hist2(const float* __restrict__ r,
                                               const unsigned* __restrict__ sel,
                                               unsigned* __restrict__ hist2) {
    __shared__ unsigned lh[256];
    lh[threadIdx.x] = 0;
    __syncthreads();
    unsigned b1 = sel[0];
    int idx = blockIdx.x * blockDim.x + threadIdx.x;
    int stride = gridDim.x * blockDim.x;
    const float4* r4 = (const float4*)r;
    for (int i = idx; i < NPIX / 4; i += stride) {
        float4 v = r4[i];
        unsigned u;
        u = fmap(v.x); if ((u >> 24) == b1) atomicAdd(&lh[(u >> 16) & 0xFF], 1u);
        u = fmap(v.y); if ((u >> 24) == b1) atomicAdd(&lh[(u >> 16) & 0xFF], 1u);
        u = fmap(v.z); if ((u >> 24) == b1) atomicAdd(&lh[(u >> 16) & 0xFF], 1u);
        u = fmap(v.w); if ((u >> 24) == b1) atomicAdd(&lh[(u >> 16) & 0xFF], 1u);
    }
    __syncthreads();
    if (lh[threadIdx.x]) atomicAdd(&hist2[threadIdx.x], lh[threadIdx.x]);
}

// ---------------- hist3 (R11-proven body; grid 2048) ----------------
__global__ __launch_bounds__(256) void k_hist3(const float* __restrict__ r,
                                               const unsigned* __restrict__ sel,
                                               unsigned* __restrict__ hist3) {
    unsigned top16 = (sel[0] << 8) | sel[2];
    int idx = blockIdx.x * blockDim.x + threadIdx.x;
    int stride = gridDim.x * blockDim.x;
    const float4* r4 = (const float4*)r;
    for (int i = idx; i < NPIX / 4; i += stride) {
        float4 v = r4[i];
        unsigned u;
        u = fmap(v.x); if ((u >> 16) == top16) atomicAdd(&hist3[u & 0xFFFF], 1u);
        u = fmap(v.y); if ((u >> 16) == top16) atomicAdd(&hist3[u & 0xFFFF], 1u);
        u = fmap(v.z); if ((u >> 16) == top16) atomicAdd(&hist3[u & 0xFFFF], 1u);
        u = fmap(v.w); if ((u >> 16) == top16) atomicAdd(&hist3[u & 0xFFFF], 1u);
    }
}

// ---------------- parallel 64K-bin scan (R11-proven) ----------------
__global__ __launch_bounds__(1024) void k_scan64k(const unsigned* __restrict__ hist3,
                                                  unsigned* __restrict__ sel) {
    __shared__ unsigned ps[1024];
    int t = threadIdx.x;
    const uint4* h4 = (const uint4*)hist3;
    unsigned sum = 0;
#pragma unroll
    for (int i = 0; i < 16; ++i) {
        uint4 v = h4[t * 16 + i];
        sum += v.x + v.y + v.z + v.w;
    }
    ps[t] = sum;
    __syncthreads();
    for (int off = 1; off < 1024; off <<= 1) {
        unsigned v = (t >= off) ? ps[t - off] : 0u;
        __syncthreads();
        ps[t] += v;
        __syncthreads();
    }
    unsigned k = sel[3];
    unsigned inc = ps[t], cumb = inc - sum;
    if (k >= cumb && k < inc) {
        unsigned rem = k - cumb;
        unsigned cum = 0, b3 = 0;
        for (int i = 0; i < 64; ++i) {
            unsigned c = hist3[t * 64 + i];
            if (rem < cum + c) { b3 = (unsigned)(t * 64 + i); break; }
            cum += c;
        }
        unsigned med_u = (sel[0] << 24) | (sel[2] << 16) | b3;
        unsigned bits = (med_u & 0x80000000u) ? (med_u & 0x7FFFFFFFu) : ~med_u;
        ((float*)sel)[6] = __uint_as_float(bits);
    }
}

// ---------------- Pass D: threshold + separable 7x7 maxpool + NMS (R11-proven) ----------------
#define RT(r,c) smem[(r)*72 + (c)]
#define HM(r,c) smem[2736 + (r)*64 + (c)]

__global__ __launch_bounds__(NT) void k_final(const float* __restrict__ r,
                                              const unsigned* __restrict__ sel,
                                              float* __restrict__ out) {
    __shared__ float smem[5168];
    float med = ((const float*)sel)[6];
    int tl = threadIdx.x;
    int bx = blockIdx.x & (NBX - 1);
    int by = blockIdx.x >> 6;
    int tx0 = bx * TSX, ty0 = by * TSY;
    bool interior = ((unsigned)(bx - 1) < 62u) && ((unsigned)(by - 1) < 62u);
    const float NINF = -INFINITY;

#pragma unroll
    for (int it = 0; it < 2; ++it) {
        int task = tl + it * NT;
        if (task < 684) {
            int row = task / 18, g = task - row * 18;
            int gy = ty0 - 3 + row;
            int gx0 = tx0 - 4 + 4 * g;
            float4 v;
            if (interior) {
                v = *(const float4*)&r[(size_t)gy * W + gx0];
            } else {
                v = make_float4(NINF, NINF, NINF, NINF);
                if ((unsigned)gy < H) {
                    if ((unsigned)gx0 <= (unsigned)(W - 4)) {
                        v = *(const float4*)&r[(size_t)gy * W + gx0];
                    } else {
                        float* pv = (float*)&v;
#pragma unroll
                        for (int k = 0; k < 4; ++k) {
                            int c = gx0 + k;
                            if ((unsigned)c < W) pv[k] = r[(size_t)gy * W + c];
                        }
                    }
                }
            }
            st4s(&RT(row, 4 * g), v);
        }
    }
    __syncthreads();

#pragma unroll
    for (int it = 0; it < 2; ++it) {
        int task = tl + it * NT;
        if (task < 608) {
            int row = task >> 4, c0 = (task & 15) << 2;
            float w[12];
            ld12(&RT(row, c0), w);
            float th[11];
#pragma unroll
            for (int j = 1; j <= 10; ++j) {
                float v = w[j];
                th[j] = (v > med) ? v : ((v == NINF) ? NINF : 0.f);
            }
            float4 m4;
            float* pm = (float*)&m4;
#pragma unroll
            for (int k = 0; k < 4; ++k) {
                float m = th[k + 1];
#pragma unroll
                for (int b = 2; b < 8; ++b) m = fmaxf(m, th[k + b]);
                pm[k] = m;
            }
            st4s(&HM(row, c0), m4);
        }
    }
    __syncthreads();

    {
        int ii = tl >> 4, c0 = (tl & 15) << 2;
        float4 m = ld4s(&HM(ii, c0));
#pragma unroll
        for (int a = 1; a < 7; ++a) {
            float4 h = ld4s(&HM(ii + a, c0));
            m.x = fmaxf(m.x, h.x); m.y = fmaxf(m.y, h.y);
            m.z = fmaxf(m.z, h.z); m.w = fmaxf(m.w, h.w);
        }
        float4 rv = ld4s(&RT(ii + 3, c0 + 4));
        float4 o;
        float tvx = (rv.x > med) ? rv.x : 0.f;
        float tvy = (rv.y > med) ? rv.y : 0.f;
        float tvz = (rv.z > med) ? rv.z : 0.f;
        float tvw = (rv.w > med) ? rv.w : 0.f;
        o.x = (m.x == tvx) ? rv.x : 0.f;
        o.y = (m.y == tvy) ? rv.y : 0.f;
        o.z = (m.z == tvz) ? rv.z : 0.f;
        o.w = (m.w == tvw) ? rv.w : 0.f;
        st4s(&out[(size_t)(ty0 + ii) * W + tx0 + c0], o);
    }
}

extern "C" void kernel_launch(void* const* d_in, const int* in_sizes, int n_in,
                              void* d_out, int out_size, void* d_ws, size_t ws_size,
                              hipStream_t stream) {
    const float* x = (const float*)d_in[0];
    const float* gw = (const float*)d_in[2];
    float* out = (float*)d_out;

    char* ws = (char*)d_ws;
    float* r = (float*)ws;
    unsigned* base = (unsigned*)(ws + (size_t)NPIX * 4);
    unsigned* hist1 = base;            // 256
    unsigned* hist2 = base + 256;      // 256
    unsigned* hist3 = base + 512;      // 65536
    unsigned* sel   = base + 66048;    // 16

    // zero hist1+hist2+hist3+sel in one contiguous memset
    hipMemsetAsync(base, 0, 66064u * sizeof(unsigned), stream);

    k_response<<<64 * 128, 256, 0, stream>>>(x, gw, r, hist1);   // 8192 blocks, 64x16 tiles
    k_scan256<<<1, 256, 0, stream>>>(hist1, sel, -1, 0);
    k_hist2<<<2048, 256, 0, stream>>>(r, sel, hist2);
    k_scan256<<<1, 256, 0, stream>>>(hist2, sel, 1, 2);
    k_hist3<<<2048, 256, 0, stream>>>(r, sel, hist3);
    k_scan64k<<<1, 1024, 0, stream>>>(hist3, sel);
    k_final<<<64 * 64, NT, 0, stream>>>(r, sel, out);            // 4096 blocks, 64x32 tiles
}

// Round 16
// 130.331 us; speedup vs baseline: 1.4838x; 1.4838x over previous
//
#include <hip/hip_runtime.h>
#include <hip/hip_bf16.h>
#include <math.h>

#define H 2048
#define W 4096
#define NPIX (H * W)
#define KSEL 4194303u   // (N-1)/2, 0-indexed order statistic for lower median
#define NT 512          // threads per tile block
#define TSX 64          // tile width
#define TSY 32          // tile height
#define NBX (W / TSX)   // 64

__device__ __forceinline__ unsigned fmap(float f) {
    unsigned u = __float_as_uint(f);
    return (u & 0x80000000u) ? ~u : (u | 0x80000000u);
}
__device__ __forceinline__ float4 ld4s(const float* p) { return *(const float4*)p; }
__device__ __forceinline__ void st4s(float* p, float4 v) { *(float4*)p = v; }
__device__ __forceinline__ void ld12(const float* p, float* d) {
    float4 a = ld4s(p), b = ld4s(p + 4), c = ld4s(p + 8);
    d[0]=a.x; d[1]=a.y; d[2]=a.z; d[3]=a.w;
    d[4]=b.x; d[5]=b.y; d[6]=b.z; d[7]=b.w;
    d[8]=c.x; d[9]=c.y; d[10]=c.z; d[11]=c.w;
}

// ---------------- Pass A: fused sobel+hgauss (R14-proven body), LDS trimmed to 4 blocks/CU ----------------
// sx stride 76->72, h stride 68->64: SMF 10176 floats = 40704 B -> 4 blocks/CU (vs 3).
// Both strides are <=2-way bank patterns (free). Register pins retained (R14-proven).
// LDS layout (floats):
//   sx : 0    .. 2880   (40 rows x 72)  [lh 256 uints overlay @0 after fused phase]
//   h0 : 2880 .. 5312   (38 rows x 64)
//   h1 : 5312 .. 7744
//   h2 : 7744 .. 10176
#define SMF 10176
#define SXA(r,c) smem[(r)*72 + (c)]
#define H0A(r,c) smem[2880 + (r)*64 + (c)]
#define H1A(r,c) smem[5312 + (r)*64 + (c)]
#define H2A(r,c) smem[7744 + (r)*64 + (c)]

__global__ __launch_bounds__(NT) void k_response(const float* __restrict__ x,
                                                 const float* __restrict__ gw,
                                                 float* __restrict__ r,
                                                 unsigned* __restrict__ hist1) {
    __shared__ float smem[SMF];
    unsigned* lh = (unsigned*)smem;   // overlays sx (dead after fused phase)

    int tl = threadIdx.x;
    int bx = blockIdx.x & (NBX - 1);
    int by = blockIdx.x >> 6;
    int tx0 = bx * TSX, ty0 = by * TSY;
    bool interior = ((unsigned)(bx - 1) < 62u) && ((unsigned)(by - 1) < 62u);

    float hwr[7], vwr[7];
    float g33 = gw[24];
#pragma unroll
    for (int b = 0; b < 7; ++b) hwr[b] = gw[21 + b];
#pragma unroll
    for (int a = 0; a < 7; ++a) vwr[a] = gw[a * 7 + 3] / g33;

    // ---- phase 1: load x tile rows ty0-4..ty0+35 (40), cols tx0-4..tx0+67 (72 = 18 groups) ----
#pragma unroll
    for (int it = 0; it < 2; ++it) {
        int task = tl + it * NT;
        if (task < 720) {
            int row = task / 18, g = task - row * 18;
            int gy = ty0 - 4 + row;
            int gx0 = tx0 - 4 + 4 * g;
            float4 v;
            if (interior) {
                v = *(const float4*)&x[(size_t)gy * W + gx0];
            } else {
                v = make_float4(0.f, 0.f, 0.f, 0.f);
                if ((unsigned)gy < H) {
                    if ((unsigned)gx0 <= (unsigned)(W - 4)) {
                        v = *(const float4*)&x[(size_t)gy * W + gx0];
                    } else {
                        float* vv = (float*)&v;
#pragma unroll
                        for (int k = 0; k < 4; ++k) {
                            int c = gx0 + k;
                            if ((unsigned)c < W) vv[k] = x[(size_t)gy * W + c];
                        }
                    }
                }
            }
            st4s(&SXA(row, 4 * g), v);
        }
    }
    __syncthreads();

    // ---- phase 2 (fused): sobel on the fly + horizontal gaussian of products ----
    // task (row 0..37, c0 0..60): h[row][c0..c0+3]; gradient p at image col tx0+c0+p-3,
    // image row ty0-3+row. Register-pinned staging (R14-proven) prevents LDS re-reads.
#pragma unroll
    for (int it = 0; it < 2; ++it) {
        int task = tl + it * NT;
        if (task < 608) {
            int row = task >> 4;
            int c0 = (task & 15) << 2;
            int xbase = tx0 + c0 - 3;

            float x0[12], x1[12], x2[12];
            ld12(&SXA(row, c0), x0);
            ld12(&SXA(row + 1, c0), x1);
            ld12(&SXA(row + 2, c0), x2);
#pragma unroll
            for (int p = 0; p < 12; ++p)
                asm volatile("" : "+v"(x0[p]), "+v"(x1[p]), "+v"(x2[p]));

            float px[10], py[10], pxy[10];
            if (interior) {
#pragma unroll
                for (int p = 0; p < 10; ++p) {
                    float ix = (x0[p + 2] - x0[p]) + 2.f * (x1[p + 2] - x1[p]) + (x2[p + 2] - x2[p]);
                    float iy = (x2[p] - x0[p]) + 2.f * (x2[p + 1] - x0[p + 1]) + (x2[p + 2] - x0[p + 2]);
                    px[p] = ix * ix; py[p] = iy * iy; pxy[p] = ix * iy;
                }
            } else {
                int rowOK = ((unsigned)(ty0 - 3 + row) < H);
#pragma unroll
                for (int p = 0; p < 10; ++p) {
                    float ix = (x0[p + 2] - x0[p]) + 2.f * (x1[p + 2] - x1[p]) + (x2[p + 2] - x2[p]);
                    float iy = (x2[p] - x0[p]) + 2.f * (x2[p + 1] - x0[p + 1]) + (x2[p + 2] - x0[p + 2]);
                    bool ok = rowOK && ((unsigned)(xbase + p) < W);
                    ix = ok ? ix : 0.f;
                    iy = ok ? iy : 0.f;
                    px[p] = ix * ix; py[p] = iy * iy; pxy[p] = ix * iy;
                }
            }

            float4 s0, s1, s2;
            float* q0 = (float*)&s0; float* q1 = (float*)&s1; float* q2 = (float*)&s2;
#pragma unroll
            for (int k = 0; k < 4; ++k) {
                float a0 = 0.f, a1 = 0.f, a2 = 0.f;
#pragma unroll
                for (int b = 0; b < 7; ++b) {
                    float w = hwr[b];
                    a0 += w * px[k + b];
                    a1 += w * py[k + b];
                    a2 += w * pxy[k + b];
                }
                q0[k] = a0; q1[k] = a1; q2[k] = a2;
            }
            st4s(&H0A(row, c0), s0);
            st4s(&H1A(row, c0), s1);
            st4s(&H2A(row, c0), s2);
        }
    }
    __syncthreads();

    // ---- zero lh (overlays sx, now dead) ----
    if (tl < 256) lh[tl] = 0;
    __syncthreads();

    // ---- vertical gaussian + response + merged-bin histogram (R11/R14-proven) ----
    {
        int ii = tl >> 4, c0 = (tl & 15) << 2;
        float4 a0 = make_float4(0.f, 0.f, 0.f, 0.f), a1 = a0, a2 = a0;
#pragma unroll
        for (int a = 0; a < 7; ++a) {
            float w = vwr[a];
            float4 h0v = ld4s(&H0A(ii + a, c0));
            float4 h1v = ld4s(&H1A(ii + a, c0));
            float4 h2v = ld4s(&H2A(ii + a, c0));
            a0.x += w * h0v.x; a0.y += w * h0v.y; a0.z += w * h0v.z; a0.w += w * h0v.w;
            a1.x += w * h1v.x; a1.y += w * h1v.y; a1.z += w * h1v.z; a1.w += w * h1v.w;
            a2.x += w * h2v.x; a2.y += w * h2v.y; a2.z += w * h2v.z; a2.w += w * h2v.w;
        }
        float* sxx = (float*)&a0; float* syy = (float*)&a1; float* sxy = (float*)&a2;
        float4 rv4;
        float* prv = (float*)&rv4;
#pragma unroll
        for (int k = 0; k < 4; ++k) {
            float tr = sxx[k] + syy[k];
            prv[k] = sxx[k] * syy[k] - sxy[k] * sxy[k] - 0.05f * tr * tr;
        }
        st4s(&r[(size_t)(ty0 + ii) * W + tx0 + c0], rv4);
        unsigned bn[4];
#pragma unroll
        for (int k = 0; k < 4; ++k) bn[k] = fmap(prv[k]) >> 24;
#pragma unroll
        for (int i = 0; i < 4; ++i) {
            bool dup = false;
            unsigned cnt = 1;
#pragma unroll
            for (int j = 0; j < 4; ++j) {
                if (j < i) dup = dup || (bn[j] == bn[i]);
                if (j > i) cnt += (bn[j] == bn[i]) ? 1u : 0u;
            }
            if (!dup) atomicAdd(&lh[bn[i]], cnt);
        }
    }
    __syncthreads();
    if (tl < 256 && lh[tl]) atomicAdd(&hist1[tl], lh[tl]);
}

// ---------------- 256-bin scan (R11-proven) ----------------
__global__ __launch_bounds__(256) void k_scan256(const unsigned* __restrict__ hist,
                                                 unsigned* __restrict__ sel,
                                                 int in_rank_idx, int out_base) {
    __shared__ unsigned s[256];
    int t = threadIdx.x;
    unsigned c = hist[t];
    s[t] = c;
    __syncthreads();
    for (int off = 1; off < 256; off <<= 1) {
        unsigned v = (t >= off) ? s[t - off] : 0u;
        __syncthreads();
        s[t] += v;
        __syncthreads();
    }
    unsigned k = (in_rank_idx < 0) ? KSEL : sel[in_rank_idx];
    unsigned cumb = s[t] - c;
    if (k >= cumb && k < s[t]) {
        sel[out_base] = (unsigned)t;
        sel[out_base + 1] = k - cumb;
    }
}

// ---------------- hist2 (R11-proven; grid 1024) ----------------
__global__ __launch_bounds__(256) void k_hist2(const float* __restrict__ r,
                                               const unsigned* __restrict__ sel,
                                               unsigned* __restrict__ hist2) {
    __shared__ unsigned lh[256];
    lh[threadIdx.x] = 0;
    __syncthreads();
    unsigned b1 = sel[0];
    int idx = blockIdx.x * blockDim.x + threadIdx.x;
    int stride = gridDim.x * blockDim.x;
    const float4* r4 = (const float4*)r;
    for (int i = idx; i < NPIX / 4; i += stride) {
        float4 v = r4[i];
        unsigned u;
        u = fmap(v.x); if ((u >> 24) == b1) atomicAdd(&lh[(u >> 16) & 0xFF], 1u);
        u = fmap(v.y); if ((u >> 24) == b1) atomicAdd(&lh[(u >> 16) & 0xFF], 1u);
        u = fmap(v.z); if ((u >> 24) == b1) atomicAdd(&lh[(u >> 16) & 0xFF], 1u);
        u = fmap(v.w); if ((u >> 24) == b1) atomicAdd(&lh[(u >> 16) & 0xFF], 1u);
    }
    __syncthreads();
    if (lh[threadIdx.x]) atomicAdd(&hist2[threadIdx.x], lh[threadIdx.x]);
}

// ---------------- hist3 (R11-proven; grid 1024) ----------------
__global__ __launch_bounds__(256) void k_hist3(const float* __restrict__ r,
                                               const unsigned* __restrict__ sel,
                                               unsigned* __restrict__ hist3) {
    unsigned top16 = (sel[0] << 8) | sel[2];
    int idx = blockIdx.x * blockDim.x + threadIdx.x;
    int stride = gridDim.x * blockDim.x;
    const float4* r4 = (const float4*)r;
    for (int i = idx; i < NPIX / 4; i += stride) {
        float4 v = r4[i];
        unsigned u;
        u = fmap(v.x); if ((u >> 16) == top16) atomicAdd(&hist3[u & 0xFFFF], 1u);
        u = fmap(v.y); if ((u >> 16) == top16) atomicAdd(&hist3[u & 0xFFFF], 1u);
        u = fmap(v.z); if ((u >> 16) == top16) atomicAdd(&hist3[u & 0xFFFF], 1u);
        u = fmap(v.w); if ((u >> 16) == top16) atomicAdd(&hist3[u & 0xFFFF], 1u);
    }
}

// ---------------- parallel 64K-bin scan (R11-proven) ----------------
__global__ __launch_bounds__(1024) void k_scan64k(const unsigned* __restrict__ hist3,
                                                  unsigned* __restrict__ sel) {
    __shared__ unsigned ps[1024];
    int t = threadIdx.x;
    const uint4* h4 = (const uint4*)hist3;
    unsigned sum = 0;
#pragma unroll
    for (int i = 0; i < 16; ++i) {
        uint4 v = h4[t * 16 + i];
        sum += v.x + v.y + v.z + v.w;
    }
    ps[t] = sum;
    __syncthreads();
    for (int off = 1; off < 1024; off <<= 1) {
        unsigned v = (t >= off) ? ps[t - off] : 0u;
        __syncthreads();
        ps[t] += v;
        __syncthreads();
    }
    unsigned k = sel[3];
    unsigned inc = ps[t], cumb = inc - sum;
    if (k >= cumb && k < inc) {
        unsigned rem = k - cumb;
        unsigned cum = 0, b3 = 0;
        for (int i = 0; i < 64; ++i) {
            unsigned c = hist3[t * 64 + i];
            if (rem < cum + c) { b3 = (unsigned)(t * 64 + i); break; }
            cum += c;
        }
        unsigned med_u = (sel[0] << 24) | (sel[2] << 16) | b3;
        unsigned bits = (med_u & 0x80000000u) ? (med_u & 0x7FFFFFFFu) : ~med_u;
        ((float*)sel)[6] = __uint_as_float(bits);
    }
}

// ---------------- Pass D: threshold + separable 7x7 maxpool + NMS (R11-proven) ----------------
#define RT(r,c) smem[(r)*72 + (c)]
#define HM(r,c) smem[2736 + (r)*64 + (c)]

__global__ __launch_bounds__(NT) void k_final(const float* __restrict__ r,
                                              const unsigned* __restrict__ sel,
                                              float* __restrict__ out) {
    __shared__ float smem[5168];
    float med = ((const float*)sel)[6];
    int tl = threadIdx.x;
    int bx = blockIdx.x & (NBX - 1);
    int by = blockIdx.x >> 6;
    int tx0 = bx * TSX, ty0 = by * TSY;
    bool interior = ((unsigned)(bx - 1) < 62u) && ((unsigned)(by - 1) < 62u);
    const float NINF = -INFINITY;

#pragma unroll
    for (int it = 0; it < 2; ++it) {
        int task = tl + it * NT;
        if (task < 684) {
            int row = task / 18, g = task - row * 18;
            int gy = ty0 - 3 + row;
            int gx0 = tx0 - 4 + 4 * g;
            float4 v;
            if (interior) {
                v = *(const float4*)&r[(size_t)gy * W + gx0];
            } else {
                v = make_float4(NINF, NINF, NINF, NINF);
                if ((unsigned)gy < H) {
                    if ((unsigned)gx0 <= (unsigned)(W - 4)) {
                        v = *(const float4*)&r[(size_t)gy * W + gx0];
                    } else {
                        float* pv = (float*)&v;
#pragma unroll
                        for (int k = 0; k < 4; ++k) {
                            int c = gx0 + k;
                            if ((unsigned)c < W) pv[k] = r[(size_t)gy * W + c];
                        }
                    }
                }
            }
            st4s(&RT(row, 4 * g), v);
        }
    }
    __syncthreads();

#pragma unroll
    for (int it = 0; it < 2; ++it) {
        int task = tl + it * NT;
        if (task < 608) {
            int row = task >> 4, c0 = (task & 15) << 2;
            float w[12];
            ld12(&RT(row, c0), w);
            float th[11];
#pragma unroll
            for (int j = 1; j <= 10; ++j) {
                float v = w[j];
                th[j] = (v > med) ? v : ((v == NINF) ? NINF : 0.f);
            }
            float4 m4;
            float* pm = (float*)&m4;
#pragma unroll
            for (int k = 0; k < 4; ++k) {
                float m = th[k + 1];
#pragma unroll
                for (int b = 2; b < 8; ++b) m = fmaxf(m, th[k + b]);
                pm[k] = m;
            }
            st4s(&HM(row, c0), m4);
        }
    }
    __syncthreads();

    {
        int ii = tl >> 4, c0 = (tl & 15) << 2;
        float4 m = ld4s(&HM(ii, c0));
#pragma unroll
        for (int a = 1; a < 7; ++a) {
            float4 h = ld4s(&HM(ii + a, c0));
            m.x = fmaxf(m.x, h.x); m.y = fmaxf(m.y, h.y);
            m.z = fmaxf(m.z, h.z); m.w = fmaxf(m.w, h.w);
        }
        float4 rv = ld4s(&RT(ii + 3, c0 + 4));
        float4 o;
        float tvx = (rv.x > med) ? rv.x : 0.f;
        float tvy = (rv.y > med) ? rv.y : 0.f;
        float tvz = (rv.z > med) ? rv.z : 0.f;
        float tvw = (rv.w > med) ? rv.w : 0.f;
        o.x = (m.x == tvx) ? rv.x : 0.f;
        o.y = (m.y == tvy) ? rv.y : 0.f;
        o.z = (m.z == tvz) ? rv.z : 0.f;
        o.w = (m.w == tvw) ? rv.w : 0.f;
        st4s(&out[(size_t)(ty0 + ii) * W + tx0 + c0], o);
    }
}

extern "C" void kernel_launch(void* const* d_in, const int* in_sizes, int n_in,
                              void* d_out, int out_size, void* d_ws, size_t ws_size,
                              hipStream_t stream) {
    const float* x = (const float*)d_in[0];
    const float* gw = (const float*)d_in[2];
    float* out = (float*)d_out;

    char* ws = (char*)d_ws;
    float* r = (float*)ws;
    unsigned* base = (unsigned*)(ws + (size_t)NPIX * 4);
    unsigned* hist1 = base;            // 256
    unsigned* hist2 = base + 256;      // 256
    unsigned* hist3 = base + 512;      // 65536
    unsigned* sel   = base + 66048;    // 16

    // zero hist1+hist2+hist3+sel in one contiguous memset
    hipMemsetAsync(base, 0, 66064u * sizeof(unsigned), stream);

    int nblk = 64 * 64; // 4096 blocks, 64x32 tiles
    k_response<<<nblk, NT, 0, stream>>>(x, gw, r, hist1);
    k_scan256<<<1, 256, 0, stream>>>(hist1, sel, -1, 0);
    k_hist2<<<1024, 256, 0, stream>>>(r, sel, hist2);
    k_scan256<<<1, 256, 0, stream>>>(hist2, sel, 1, 2);
    k_hist3<<<1024, 256, 0, stream>>>(r, sel, hist3);
    k_scan64k<<<1, 1024, 0, stream>>>(hist3, sel);
    k_final<<<nblk, NT, 0, stream>>>(r, sel, out);
}